// Round 6
// baseline (215.639 us; speedup 1.0000x reference)
//
#include <hip/hip_runtime.h>
#include <hip/hip_bf16.h>

#define F_ 16384
#define D_ 768
#define C_ 16
#define BS_ 512
#define M_ (F_*C_)

static __device__ __forceinline__ float bf2f(unsigned short u) {
    return __uint_as_float(((unsigned int)u) << 16);
}
static __device__ __forceinline__ unsigned short f2bf(float f) {
    return __bfloat16_as_ushort(__float2bfloat16(f));
}

// int8 dot4: d = a.b + c over 4 packed signed bytes
#if __has_builtin(__builtin_amdgcn_sdot4)
static __device__ __forceinline__ int sdot4(unsigned int a, unsigned int b, int c) {
    return __builtin_amdgcn_sdot4((int)a, (int)b, c, false);
}
#else
static __device__ __forceinline__ int sdot4(unsigned int a, unsigned int b, int c) {
#pragma unroll
    for (int i = 0; i < 4; ++i)
        c += (int)(signed char)(a >> (8 * i)) * (int)(signed char)(b >> (8 * i));
    return c;
}
#endif

// exact-i32 chain over 8 packed dwords (32 int8 MACs)
static __device__ __forceinline__ int chain8(uint4 ea, uint4 eb, uint4 ga, uint4 gb) {
    int a = 0;
    a = sdot4(ea.x, ga.x, a); a = sdot4(ea.y, ga.y, a);
    a = sdot4(ea.z, ga.z, a); a = sdot4(ea.w, ga.w, a);
    a = sdot4(eb.x, gb.x, a); a = sdot4(eb.y, gb.y, a);
    a = sdot4(eb.z, gb.z, a); a = sdot4(eb.w, gb.w, a);
    return a;
}

// ---------------------------------------------------------------------------
// Transpose + block-int8 quantize: up_decoder fp32 [D, F] -> dec8 int8 [F, D]
// with per-(f, 64d-block) fp32 scales [F][16] (12 used). (unchanged from R5)
// ---------------------------------------------------------------------------
__global__ __launch_bounds__(256) void k_transpose_i8(const float* __restrict__ in,
                                                      unsigned char* __restrict__ out,
                                                      float* __restrict__ scales) {
    __shared__ float tile[64][65];      // [d_local][f_local], +1 pad
    __shared__ float pmax[4][64];       // partial |max| per quarter x f_local
    int c4 = threadIdx.x & 15;          // float4 column (f)
    int r  = threadIdx.x >> 4;          // 0..15 (d)
    int fbase = blockIdx.x * 64;
    int dbase = blockIdx.y * 64;
#pragma unroll
    for (int k = 0; k < 4; ++k) {
        int drow = r + k * 16;
        float4 v = *(const float4*)(in + (size_t)(dbase + drow) * F_ + fbase + c4 * 4);
        tile[drow][c4 * 4 + 0] = v.x;
        tile[drow][c4 * 4 + 1] = v.y;
        tile[drow][c4 * 4 + 2] = v.z;
        tile[drow][c4 * 4 + 3] = v.w;
    }
    __syncthreads();
    {
        int c = threadIdx.x & 63;       // f_local
        int q = threadIdx.x >> 6;       // quarter of d range
        float m = 0.f;
#pragma unroll
        for (int i = 0; i < 16; ++i)
            m = fmaxf(m, fabsf(tile[q * 16 + i][c]));
        pmax[q][c] = m;
    }
    __syncthreads();
    int dp = threadIdx.x & 15;          // uint index (4 d-values each)
    int fr = threadIdx.x >> 4;          // 0..15 (f)
#pragma unroll
    for (int k = 0; k < 4; ++k) {
        int frow = fr + k * 16;
        float cmax = fmaxf(fmaxf(pmax[0][frow], pmax[1][frow]),
                           fmaxf(pmax[2][frow], pmax[3][frow]));
        float s  = cmax * (1.f / 127.f);
        float rs = cmax > 0.f ? 127.f / cmax : 0.f;
        int q0 = __float2int_rn(tile[4 * dp + 0][frow] * rs);
        int q1 = __float2int_rn(tile[4 * dp + 1][frow] * rs);
        int q2 = __float2int_rn(tile[4 * dp + 2][frow] * rs);
        int q3 = __float2int_rn(tile[4 * dp + 3][frow] * rs);
        unsigned int p = (q0 & 0xff) | ((q1 & 0xff) << 8)
                       | ((q2 & 0xff) << 16) | ((q3 & 0xff) << 24);
        *(unsigned int*)(out + (size_t)(fbase + frow) * D_ + dbase + dp * 4) = p;
        if (dp == 0)
            scales[((size_t)(fbase + frow) << 4) + (dbase >> 6)] = s;
    }
}

// ---------------------------------------------------------------------------
// k_values v6: VALU-lean regrouping. Block = 256 thr = 4 waves, 2 f's/block.
// Phase A: waves 0/2 quantize their f's enc row once into LDS (per-64-block
// scales, same grid as v5). Phase B: 8 lanes per connection; each lane owns
// 24 contiguous dwords (96 B) of the gathered row; 8-dword chunks are
// 64-block-aligned -> exact i32 sdot4 chains, only 3 cvt+fma per conn-lane,
// 3-stage reduce. Same traffic, same quantization numerics as v5.
// packed[m] = (bf16(value) << 16) | (u16)j.
// ---------------------------------------------------------------------------
__global__ __launch_bounds__(256) void k_values(const float* __restrict__ enc,
                                                const unsigned char* __restrict__ dec8,
                                                const float* __restrict__ scales,
                                                const int* __restrict__ jidx,
                                                unsigned int* __restrict__ packed) {
    __shared__ __align__(16) unsigned int enc8_lds[2][192];
    __shared__ float se_lds[2][12];
    int lane = threadIdx.x & 63;
    int wave = threadIdx.x >> 6;          // 0..3
    int fl   = wave >> 1;                 // local f: 0/1
    int f    = (blockIdx.x << 1) + fl;

    // Phase A: waves 0 and 2 quantize enc row f -> LDS (once per f)
    if ((wave & 1) == 0) {
        const float4* erow = (const float4*)(enc + (size_t)f * D_);
        float4 e0 = erow[lane], e1 = erow[lane + 64], e2 = erow[lane + 128];
        float4 ev[3] = {e0, e1, e2};
#pragma unroll
        for (int k = 0; k < 3; ++k) {
            float4 v = ev[k];
            float m = fmaxf(fmaxf(fabsf(v.x), fabsf(v.y)),
                            fmaxf(fabsf(v.z), fabsf(v.w)));
#pragma unroll
            for (int off = 1; off < 16; off <<= 1)
                m = fmaxf(m, __shfl_xor(m, off, 64));
            float rs = m > 0.f ? 127.f / m : 0.f;
            int q0 = __float2int_rn(v.x * rs);
            int q1 = __float2int_rn(v.y * rs);
            int q2 = __float2int_rn(v.z * rs);
            int q3 = __float2int_rn(v.w * rs);
            enc8_lds[fl][lane + 64 * k] = (q0 & 0xff) | ((q1 & 0xff) << 8)
                                        | ((q2 & 0xff) << 16) | ((q3 & 0xff) << 24);
            if ((lane & 15) == 0)
                se_lds[fl][4 * k + (lane >> 4)] = m * (1.f / 127.f);
        }
    }
    __syncthreads();

    // Phase B: conn t handled by an 8-lane group; lane p owns dwords 24p..24p+23
    int t = ((wave & 1) << 3) + (lane >> 3);  // 0..15
    int p = lane & 7;
    int j = jidx[(f << 4) + t];

    const uint4* grow = (const uint4*)(dec8 + (size_t)j * D_);   // 48 uint4/row
    uint4 g0 = grow[6 * p + 0], g1 = grow[6 * p + 1], g2 = grow[6 * p + 2],
          g3 = grow[6 * p + 3], g4 = grow[6 * p + 4], g5 = grow[6 * p + 5];
    const uint4* elds = (const uint4*)enc8_lds[fl];
    uint4 e0 = elds[6 * p + 0], e1 = elds[6 * p + 1], e2 = elds[6 * p + 2],
          e3 = elds[6 * p + 3], e4 = elds[6 * p + 4], e5 = elds[6 * p + 5];

    // chunk s (8 dwords) lies entirely in 64-elem block b = (3p+s)>>1
    int b0 = (3 * p) >> 1, b1 = (3 * p + 1) >> 1, b2 = (3 * p + 2) >> 1;
    const float* srow = scales + ((size_t)j << 4);
    float s0 = srow[b0] * se_lds[fl][b0];
    float s1 = srow[b1] * se_lds[fl][b1];
    float s2 = srow[b2] * se_lds[fl][b2];

    int a0 = chain8(e0, e1, g0, g1);
    int a1 = chain8(e2, e3, g2, g3);
    int a2 = chain8(e4, e5, g4, g5);
    float val = fmaf((float)a0, s0, fmaf((float)a1, s1, (float)a2 * s2));

#pragma unroll
    for (int off = 1; off < 8; off <<= 1)
        val += __shfl_down(val, off, 64);
    if (p == 0)
        packed[(f << 4) + t] = ((unsigned int)f2bf(val) << 16) | (unsigned int)j;
}

// ---------------------------------------------------------------------------
// out[bs,f] = sum_c up[bs, j]*v over the 16 connections of f.
// v6: one block per bs-pair (256 blocks), full f range per block -> the
// staged up row pair is read from HBM once instead of twice.
// ---------------------------------------------------------------------------
__global__ __launch_bounds__(512) void k_out(const float* __restrict__ up,
                                             const unsigned int* __restrict__ packed,
                                             float* __restrict__ out) {
    __shared__ unsigned int rowp[F_];   // 64 KB
    int bs0 = blockIdx.x << 1;
    const float4* u0 = (const float4*)(up + (size_t)bs0 * F_);
    const float4* u1 = (const float4*)(up + (size_t)(bs0 + 1) * F_);
#pragma unroll
    for (int k = 0; k < 8; ++k) {
        int idx = threadIdx.x + k * 512;       // float4 index
        float4 a = u0[idx];
        float4 b = u1[idx];
        uint4 p;
        p.x = ((unsigned int)f2bf(b.x) << 16) | (unsigned int)f2bf(a.x);
        p.y = ((unsigned int)f2bf(b.y) << 16) | (unsigned int)f2bf(a.y);
        p.z = ((unsigned int)f2bf(b.z) << 16) | (unsigned int)f2bf(a.z);
        p.w = ((unsigned int)f2bf(b.w) << 16) | (unsigned int)f2bf(a.w);
        ((uint4*)rowp)[idx] = p;
    }
    __syncthreads();
#pragma unroll 4
    for (int it = 0; it < 32; ++it) {
        int f = threadIdx.x + it * 512;
        const uint4* sp = (const uint4*)(packed + ((size_t)f << 4));
        float a0 = 0.f, a1 = 0.f;
#pragma unroll
        for (int q = 0; q < 4; ++q) {
            uint4 w = sp[q];
#define CONN(ww) { unsigned int p_ = rowp[(ww) & 0xffffu];                  \
                   float v_ = __uint_as_float((ww) & 0xffff0000u);          \
                   a0 += __uint_as_float(p_ << 16) * v_;                    \
                   a1 += __uint_as_float(p_ & 0xffff0000u) * v_; }
            CONN(w.x) CONN(w.y) CONN(w.z) CONN(w.w)
#undef CONN
        }
        out[(size_t)bs0 * F_ + f] = a0;
        out[(size_t)(bs0 + 1) * F_ + f] = a1;
    }
}

extern "C" void kernel_launch(void* const* d_in, const int* in_sizes, int n_in,
                              void* d_out, int out_size, void* d_ws, size_t ws_size,
                              hipStream_t stream) {
    const float* up   = (const float*)d_in[0];  // up_facts   [B,S,F]
    const float* enc  = (const float*)d_in[1];  // down_encoder [F,D]
    const float* dec  = (const float*)d_in[2];  // up_decoder [D,F]
    // d_in[3] = i_indices, unused: i[m] = m >> 4 by construction
    const int*   jidx = (const int*)d_in[4];    // j_indices  [M]
    float*       out  = (float*)d_out;

    size_t dec8_bytes  = (size_t)F_ * D_;                 // 12.6 MB (int8)
    size_t scale_bytes = (size_t)F_ * 16 * sizeof(float); // 1 MB
    unsigned char* dec8   = (unsigned char*)d_ws;
    float*         scales = (float*)((char*)d_ws + dec8_bytes);
    unsigned int*  packed = (unsigned int*)((char*)d_ws + dec8_bytes + scale_bytes);

    k_transpose_i8<<<dim3(F_ / 64, D_ / 64), 256, 0, stream>>>(dec, dec8, scales);
    k_values<<<F_ / 2, 256, 0, stream>>>(enc, dec8, scales, jidx, packed);
    k_out<<<BS_ / 2, 512, 0, stream>>>(up, packed, out);
}

// Round 7
// 204.925 us; speedup vs baseline: 1.0523x; 1.0523x over previous
//
#include <hip/hip_runtime.h>
#include <hip/hip_bf16.h>

#define F_ 16384
#define D_ 768
#define C_ 16
#define BS_ 512
#define M_ (F_*C_)

static __device__ __forceinline__ float bf2f(unsigned short u) {
    return __uint_as_float(((unsigned int)u) << 16);
}
static __device__ __forceinline__ unsigned short f2bf(float f) {
    return __bfloat16_as_ushort(__float2bfloat16(f));
}

// int8 dot4: d = a.b + c over 4 packed signed bytes
#if __has_builtin(__builtin_amdgcn_sdot4)
static __device__ __forceinline__ int sdot4(unsigned int a, unsigned int b, int c) {
    return __builtin_amdgcn_sdot4((int)a, (int)b, c, false);
}
#else
static __device__ __forceinline__ int sdot4(unsigned int a, unsigned int b, int c) {
#pragma unroll
    for (int i = 0; i < 4; ++i)
        c += (int)(signed char)(a >> (8 * i)) * (int)(signed char)(b >> (8 * i));
    return c;
}
#endif

// exact-i32 chain over 8 packed dwords (32 int8 MACs)
static __device__ __forceinline__ int chain8(uint4 ea, uint4 eb, uint4 ga, uint4 gb) {
    int a = 0;
    a = sdot4(ea.x, ga.x, a); a = sdot4(ea.y, ga.y, a);
    a = sdot4(ea.z, ga.z, a); a = sdot4(ea.w, ga.w, a);
    a = sdot4(eb.x, gb.x, a); a = sdot4(eb.y, gb.y, a);
    a = sdot4(eb.z, gb.z, a); a = sdot4(eb.w, gb.w, a);
    return a;
}

// ---------------------------------------------------------------------------
// Transpose + block-int8 quantize: up_decoder fp32 [D, F] -> dec8 int8 [F, D]
// with per-(f, 64d-block) fp32 scales [F][16] (12 used). (unchanged)
// ---------------------------------------------------------------------------
__global__ __launch_bounds__(256) void k_transpose_i8(const float* __restrict__ in,
                                                      unsigned char* __restrict__ out,
                                                      float* __restrict__ scales) {
    __shared__ float tile[64][65];      // [d_local][f_local], +1 pad
    __shared__ float pmax[4][64];       // partial |max| per quarter x f_local
    int c4 = threadIdx.x & 15;          // float4 column (f)
    int r  = threadIdx.x >> 4;          // 0..15 (d)
    int fbase = blockIdx.x * 64;
    int dbase = blockIdx.y * 64;
#pragma unroll
    for (int k = 0; k < 4; ++k) {
        int drow = r + k * 16;
        float4 v = *(const float4*)(in + (size_t)(dbase + drow) * F_ + fbase + c4 * 4);
        tile[drow][c4 * 4 + 0] = v.x;
        tile[drow][c4 * 4 + 1] = v.y;
        tile[drow][c4 * 4 + 2] = v.z;
        tile[drow][c4 * 4 + 3] = v.w;
    }
    __syncthreads();
    {
        int c = threadIdx.x & 63;       // f_local
        int q = threadIdx.x >> 6;       // quarter of d range
        float m = 0.f;
#pragma unroll
        for (int i = 0; i < 16; ++i)
            m = fmaxf(m, fabsf(tile[q * 16 + i][c]));
        pmax[q][c] = m;
    }
    __syncthreads();
    int dp = threadIdx.x & 15;          // uint index (4 d-values each)
    int fr = threadIdx.x >> 4;          // 0..15 (f)
#pragma unroll
    for (int k = 0; k < 4; ++k) {
        int frow = fr + k * 16;
        float cmax = fmaxf(fmaxf(pmax[0][frow], pmax[1][frow]),
                           fmaxf(pmax[2][frow], pmax[3][frow]));
        float s  = cmax * (1.f / 127.f);
        float rs = cmax > 0.f ? 127.f / cmax : 0.f;
        int q0 = __float2int_rn(tile[4 * dp + 0][frow] * rs);
        int q1 = __float2int_rn(tile[4 * dp + 1][frow] * rs);
        int q2 = __float2int_rn(tile[4 * dp + 2][frow] * rs);
        int q3 = __float2int_rn(tile[4 * dp + 3][frow] * rs);
        unsigned int p = (q0 & 0xff) | ((q1 & 0xff) << 8)
                       | ((q2 & 0xff) << 16) | ((q3 & 0xff) << 24);
        *(unsigned int*)(out + (size_t)(fbase + frow) * D_ + dbase + dp * 4) = p;
        if (dp == 0)
            scales[((size_t)(fbase + frow) << 4) + (dbase >> 6)] = s;
    }
}

// ---------------------------------------------------------------------------
// k_values v6 (unchanged): VALU-lean regrouping. Block = 4 waves, 2 f's.
// Phase A: waves 0/2 quantize enc rows once into LDS. Phase B: 8 lanes per
// connection, exact-i32 sdot4 chains over 96 B/lane, 3 cvt+fma, 3-stage
// reduce. packed[m] = (bf16(value) << 16) | (u16)j.
// ---------------------------------------------------------------------------
__global__ __launch_bounds__(256) void k_values(const float* __restrict__ enc,
                                                const unsigned char* __restrict__ dec8,
                                                const float* __restrict__ scales,
                                                const int* __restrict__ jidx,
                                                unsigned int* __restrict__ packed) {
    __shared__ __align__(16) unsigned int enc8_lds[2][192];
    __shared__ float se_lds[2][12];
    int lane = threadIdx.x & 63;
    int wave = threadIdx.x >> 6;          // 0..3
    int fl   = wave >> 1;                 // local f: 0/1
    int f    = (blockIdx.x << 1) + fl;

    // Phase A: waves 0 and 2 quantize enc row f -> LDS (once per f)
    if ((wave & 1) == 0) {
        const float4* erow = (const float4*)(enc + (size_t)f * D_);
        float4 e0 = erow[lane], e1 = erow[lane + 64], e2 = erow[lane + 128];
        float4 ev[3] = {e0, e1, e2};
#pragma unroll
        for (int k = 0; k < 3; ++k) {
            float4 v = ev[k];
            float m = fmaxf(fmaxf(fabsf(v.x), fabsf(v.y)),
                            fmaxf(fabsf(v.z), fabsf(v.w)));
#pragma unroll
            for (int off = 1; off < 16; off <<= 1)
                m = fmaxf(m, __shfl_xor(m, off, 64));
            float rs = m > 0.f ? 127.f / m : 0.f;
            int q0 = __float2int_rn(v.x * rs);
            int q1 = __float2int_rn(v.y * rs);
            int q2 = __float2int_rn(v.z * rs);
            int q3 = __float2int_rn(v.w * rs);
            enc8_lds[fl][lane + 64 * k] = (q0 & 0xff) | ((q1 & 0xff) << 8)
                                        | ((q2 & 0xff) << 16) | ((q3 & 0xff) << 24);
            if ((lane & 15) == 0)
                se_lds[fl][4 * k + (lane >> 4)] = m * (1.f / 127.f);
        }
    }
    __syncthreads();

    // Phase B: conn t handled by an 8-lane group; lane p owns dwords 24p..24p+23
    int t = ((wave & 1) << 3) + (lane >> 3);  // 0..15
    int p = lane & 7;
    int j = jidx[(f << 4) + t];

    const uint4* grow = (const uint4*)(dec8 + (size_t)j * D_);   // 48 uint4/row
    uint4 g0 = grow[6 * p + 0], g1 = grow[6 * p + 1], g2 = grow[6 * p + 2],
          g3 = grow[6 * p + 3], g4 = grow[6 * p + 4], g5 = grow[6 * p + 5];
    const uint4* elds = (const uint4*)enc8_lds[fl];
    uint4 e0 = elds[6 * p + 0], e1 = elds[6 * p + 1], e2 = elds[6 * p + 2],
          e3 = elds[6 * p + 3], e4 = elds[6 * p + 4], e5 = elds[6 * p + 5];

    // chunk s (8 dwords) lies entirely in 64-elem block b = (3p+s)>>1
    int b0 = (3 * p) >> 1, b1 = (3 * p + 1) >> 1, b2 = (3 * p + 2) >> 1;
    const float* srow = scales + ((size_t)j << 4);
    float s0 = srow[b0] * se_lds[fl][b0];
    float s1 = srow[b1] * se_lds[fl][b1];
    float s2 = srow[b2] * se_lds[fl][b2];

    int a0 = chain8(e0, e1, g0, g1);
    int a1 = chain8(e2, e3, g2, g3);
    int a2 = chain8(e4, e5, g4, g5);
    float val = fmaf((float)a0, s0, fmaf((float)a1, s1, (float)a2 * s2));

#pragma unroll
    for (int off = 1; off < 8; off <<= 1)
        val += __shfl_down(val, off, 64);
    if (p == 0)
        packed[(f << 4) + t] = ((unsigned int)f2bf(val) << 16) | (unsigned int)j;
}

// ---------------------------------------------------------------------------
// out[bs,f] = sum_c up[bs, j]*v over the 16 connections of f.
// v7: block = (bs-pair, f-half), 1024 threads (16 waves), 64 KB LDS pair
// table -> 512 blocks, 2 blocks/CU, 32 waves/CU (double v5's latency
// hiding, 4x v6's). __launch_bounds__(1024, 8) caps VGPR at 64 so the
// 2-block residency is actually reachable.
// ---------------------------------------------------------------------------
__global__ __launch_bounds__(1024, 8) void k_out(const float* __restrict__ up,
                                                 const unsigned int* __restrict__ packed,
                                                 float* __restrict__ out) {
    __shared__ unsigned int rowp[F_];   // 64 KB
    int bs0  = (blockIdx.x >> 1) << 1;
    int half = blockIdx.x & 1;
    const float4* u0 = (const float4*)(up + (size_t)bs0 * F_);
    const float4* u1 = (const float4*)(up + (size_t)(bs0 + 1) * F_);
#pragma unroll
    for (int k = 0; k < 4; ++k) {
        int idx = threadIdx.x + k * 1024;      // float4 index (4096 total)
        float4 a = u0[idx];
        float4 b = u1[idx];
        uint4 p;
        p.x = ((unsigned int)f2bf(b.x) << 16) | (unsigned int)f2bf(a.x);
        p.y = ((unsigned int)f2bf(b.y) << 16) | (unsigned int)f2bf(a.y);
        p.z = ((unsigned int)f2bf(b.z) << 16) | (unsigned int)f2bf(a.z);
        p.w = ((unsigned int)f2bf(b.w) << 16) | (unsigned int)f2bf(a.w);
        ((uint4*)rowp)[idx] = p;
    }
    __syncthreads();
    int f0 = half << 13;                       // 0 or 8192
#pragma unroll 4
    for (int it = 0; it < 8; ++it) {
        int f = f0 + threadIdx.x + it * 1024;
        const uint4* sp = (const uint4*)(packed + ((size_t)f << 4));
        float a0 = 0.f, a1 = 0.f;
#pragma unroll
        for (int q = 0; q < 4; ++q) {
            uint4 w = sp[q];
#define CONN(ww) { unsigned int p_ = rowp[(ww) & 0xffffu];                  \
                   float v_ = __uint_as_float((ww) & 0xffff0000u);          \
                   a0 += __uint_as_float(p_ << 16) * v_;                    \
                   a1 += __uint_as_float(p_ & 0xffff0000u) * v_; }
            CONN(w.x) CONN(w.y) CONN(w.z) CONN(w.w)
#undef CONN
        }
        out[(size_t)bs0 * F_ + f] = a0;
        out[(size_t)(bs0 + 1) * F_ + f] = a1;
    }
}

extern "C" void kernel_launch(void* const* d_in, const int* in_sizes, int n_in,
                              void* d_out, int out_size, void* d_ws, size_t ws_size,
                              hipStream_t stream) {
    const float* up   = (const float*)d_in[0];  // up_facts   [B,S,F]
    const float* enc  = (const float*)d_in[1];  // down_encoder [F,D]
    const float* dec  = (const float*)d_in[2];  // up_decoder [D,F]
    // d_in[3] = i_indices, unused: i[m] = m >> 4 by construction
    const int*   jidx = (const int*)d_in[4];    // j_indices  [M]
    float*       out  = (float*)d_out;

    size_t dec8_bytes  = (size_t)F_ * D_;                 // 12.6 MB (int8)
    size_t scale_bytes = (size_t)F_ * 16 * sizeof(float); // 1 MB
    unsigned char* dec8   = (unsigned char*)d_ws;
    float*         scales = (float*)((char*)d_ws + dec8_bytes);
    unsigned int*  packed = (unsigned int*)((char*)d_ws + dec8_bytes + scale_bytes);

    k_transpose_i8<<<dim3(F_ / 64, D_ / 64), 256, 0, stream>>>(dec, dec8, scales);
    k_values<<<F_ / 2, 256, 0, stream>>>(enc, dec8, scales, jidx, packed);
    k_out<<<BS_, 1024, 0, stream>>>(up, packed, out);
}

// Round 8
// 200.895 us; speedup vs baseline: 1.0734x; 1.0201x over previous
//
#include <hip/hip_runtime.h>
#include <hip/hip_bf16.h>

#define F_ 16384
#define D_ 768
#define C_ 16
#define BS_ 512
#define M_ (F_*C_)

static __device__ __forceinline__ float bf2f(unsigned short u) {
    return __uint_as_float(((unsigned int)u) << 16);
}
static __device__ __forceinline__ unsigned short f2bf(float f) {
    return __bfloat16_as_ushort(__float2bfloat16(f));
}

// int8 dot4: d = a.b + c over 4 packed signed bytes
#if __has_builtin(__builtin_amdgcn_sdot4)
static __device__ __forceinline__ int sdot4(unsigned int a, unsigned int b, int c) {
    return __builtin_amdgcn_sdot4((int)a, (int)b, c, false);
}
#else
static __device__ __forceinline__ int sdot4(unsigned int a, unsigned int b, int c) {
#pragma unroll
    for (int i = 0; i < 4; ++i)
        c += (int)(signed char)(a >> (8 * i)) * (int)(signed char)(b >> (8 * i));
    return c;
}
#endif

// exact-i32 dot over one uint4 (16 int8 MACs)
static __device__ __forceinline__ int dot16(uint4 e, uint4 g) {
    int a = 0;
    a = sdot4(e.x, g.x, a); a = sdot4(e.y, g.y, a);
    a = sdot4(e.z, g.z, a); a = sdot4(e.w, g.w, a);
    return a;
}

// ---------------------------------------------------------------------------
// Transpose + block-int8 quantize: up_decoder fp32 [D, F] -> dec8 int8 [F, D]
// with per-(f, 64d-block) fp32 scales [F][16] (12 used). (unchanged)
// ---------------------------------------------------------------------------
__global__ __launch_bounds__(256) void k_transpose_i8(const float* __restrict__ in,
                                                      unsigned char* __restrict__ out,
                                                      float* __restrict__ scales) {
    __shared__ float tile[64][65];      // [d_local][f_local], +1 pad
    __shared__ float pmax[4][64];       // partial |max| per quarter x f_local
    int c4 = threadIdx.x & 15;          // float4 column (f)
    int r  = threadIdx.x >> 4;          // 0..15 (d)
    int fbase = blockIdx.x * 64;
    int dbase = blockIdx.y * 64;
#pragma unroll
    for (int k = 0; k < 4; ++k) {
        int drow = r + k * 16;
        float4 v = *(const float4*)(in + (size_t)(dbase + drow) * F_ + fbase + c4 * 4);
        tile[drow][c4 * 4 + 0] = v.x;
        tile[drow][c4 * 4 + 1] = v.y;
        tile[drow][c4 * 4 + 2] = v.z;
        tile[drow][c4 * 4 + 3] = v.w;
    }
    __syncthreads();
    {
        int c = threadIdx.x & 63;       // f_local
        int q = threadIdx.x >> 6;       // quarter of d range
        float m = 0.f;
#pragma unroll
        for (int i = 0; i < 16; ++i)
            m = fmaxf(m, fabsf(tile[q * 16 + i][c]));
        pmax[q][c] = m;
    }
    __syncthreads();
    int dp = threadIdx.x & 15;          // uint index (4 d-values each)
    int fr = threadIdx.x >> 4;          // 0..15 (f)
#pragma unroll
    for (int k = 0; k < 4; ++k) {
        int frow = fr + k * 16;
        float cmax = fmaxf(fmaxf(pmax[0][frow], pmax[1][frow]),
                           fmaxf(pmax[2][frow], pmax[3][frow]));
        float s  = cmax * (1.f / 127.f);
        float rs = cmax > 0.f ? 127.f / cmax : 0.f;
        int q0 = __float2int_rn(tile[4 * dp + 0][frow] * rs);
        int q1 = __float2int_rn(tile[4 * dp + 1][frow] * rs);
        int q2 = __float2int_rn(tile[4 * dp + 2][frow] * rs);
        int q3 = __float2int_rn(tile[4 * dp + 3][frow] * rs);
        unsigned int p = (q0 & 0xff) | ((q1 & 0xff) << 8)
                       | ((q2 & 0xff) << 16) | ((q3 & 0xff) << 24);
        *(unsigned int*)(out + (size_t)(fbase + frow) * D_ + dbase + dp * 4) = p;
        if (dp == 0)
            scales[((size_t)(fbase + frow) << 4) + (dbase >> 6)] = s;
    }
}

// ---------------------------------------------------------------------------
// k_values v8: line-aligned gather. Block = 4 waves, 2 f's (as v6).
// Phase A: waves 0/2 quantize enc rows once into LDS.
// Phase B: 8 lanes per connection; lane p loads uint4 index p+8i (i=0..5):
// each instruction covers bytes [128i,128i+128) of the row contiguously --
// 2 full 64B lines per instruction, 12 line-requests per row (v6's stride-96
// pattern issued 48). Each uint4 d=p+8i sits wholly in 64-elem scale block
// d>>2, so the i32 accumulation stays exact per block.
// packed[m] = (bf16(value) << 16) | (u16)j.
// ---------------------------------------------------------------------------
__global__ __launch_bounds__(256) void k_values(const float* __restrict__ enc,
                                                const unsigned char* __restrict__ dec8,
                                                const float* __restrict__ scales,
                                                const int* __restrict__ jidx,
                                                unsigned int* __restrict__ packed) {
    __shared__ __align__(16) unsigned int enc8_lds[2][192];
    __shared__ float se_lds[2][12];
    int lane = threadIdx.x & 63;
    int wave = threadIdx.x >> 6;          // 0..3
    int fl   = wave >> 1;                 // local f: 0/1
    int f    = (blockIdx.x << 1) + fl;

    // Phase A: waves 0 and 2 quantize enc row f -> LDS (once per f)
    if ((wave & 1) == 0) {
        const float4* erow = (const float4*)(enc + (size_t)f * D_);
        float4 e0 = erow[lane], e1 = erow[lane + 64], e2 = erow[lane + 128];
        float4 ev[3] = {e0, e1, e2};
#pragma unroll
        for (int k = 0; k < 3; ++k) {
            float4 v = ev[k];
            float m = fmaxf(fmaxf(fabsf(v.x), fabsf(v.y)),
                            fmaxf(fabsf(v.z), fabsf(v.w)));
#pragma unroll
            for (int off = 1; off < 16; off <<= 1)
                m = fmaxf(m, __shfl_xor(m, off, 64));
            float rs = m > 0.f ? 127.f / m : 0.f;
            int q0 = __float2int_rn(v.x * rs);
            int q1 = __float2int_rn(v.y * rs);
            int q2 = __float2int_rn(v.z * rs);
            int q3 = __float2int_rn(v.w * rs);
            enc8_lds[fl][lane + 64 * k] = (q0 & 0xff) | ((q1 & 0xff) << 8)
                                        | ((q2 & 0xff) << 16) | ((q3 & 0xff) << 24);
            if ((lane & 15) == 0)
                se_lds[fl][4 * k + (lane >> 4)] = m * (1.f / 127.f);
        }
    }
    __syncthreads();

    // Phase B: conn t handled by an 8-lane group; lane p owns uint4 p+8i
    int t = ((wave & 1) << 3) + (lane >> 3);  // 0..15
    int p = lane & 7;
    int j = jidx[(f << 4) + t];

    const uint4* grow = (const uint4*)(dec8 + (size_t)j * D_);   // 48 uint4/row
    uint4 g0 = grow[p +  0], g1 = grow[p +  8], g2 = grow[p + 16],
          g3 = grow[p + 24], g4 = grow[p + 32], g5 = grow[p + 40];
    const uint4* elds = (const uint4*)enc8_lds[fl];
    uint4 e0 = elds[p +  0], e1 = elds[p +  8], e2 = elds[p + 16],
          e3 = elds[p + 24], e4 = elds[p + 32], e5 = elds[p + 40];

    // uint4 d = p+8i lies wholly in 64-elem block b = d>>2
    const float* srow = scales + ((size_t)j << 4);
    const float* sel  = se_lds[fl];
    float val;
    {
        int b0 = (p +  0) >> 2, b1 = (p +  8) >> 2, b2 = (p + 16) >> 2;
        int b3 = (p + 24) >> 2, b4 = (p + 32) >> 2, b5 = (p + 40) >> 2;
        float v0 = (float)dot16(e0, g0) * (srow[b0] * sel[b0]);
        float v1 = (float)dot16(e1, g1) * (srow[b1] * sel[b1]);
        float v2 = (float)dot16(e2, g2) * (srow[b2] * sel[b2]);
        float v3 = (float)dot16(e3, g3) * (srow[b3] * sel[b3]);
        float v4 = (float)dot16(e4, g4) * (srow[b4] * sel[b4]);
        float v5 = (float)dot16(e5, g5) * (srow[b5] * sel[b5]);
        val = ((v0 + v1) + (v2 + v3)) + (v4 + v5);
    }

#pragma unroll
    for (int off = 1; off < 8; off <<= 1)
        val += __shfl_down(val, off, 64);
    if (p == 0)
        packed[(f << 4) + t] = ((unsigned int)f2bf(val) << 16) | (unsigned int)j;
}

// ---------------------------------------------------------------------------
// out[bs,f] = sum_c up[bs, j]*v over the 16 connections of f.
// (unchanged from v7: 1024 threads, 2 blocks/CU, 32 waves/CU)
// ---------------------------------------------------------------------------
__global__ __launch_bounds__(1024, 8) void k_out(const float* __restrict__ up,
                                                 const unsigned int* __restrict__ packed,
                                                 float* __restrict__ out) {
    __shared__ unsigned int rowp[F_];   // 64 KB
    int bs0  = (blockIdx.x >> 1) << 1;
    int half = blockIdx.x & 1;
    const float4* u0 = (const float4*)(up + (size_t)bs0 * F_);
    const float4* u1 = (const float4*)(up + (size_t)(bs0 + 1) * F_);
#pragma unroll
    for (int k = 0; k < 4; ++k) {
        int idx = threadIdx.x + k * 1024;      // float4 index (4096 total)
        float4 a = u0[idx];
        float4 b = u1[idx];
        uint4 p;
        p.x = ((unsigned int)f2bf(b.x) << 16) | (unsigned int)f2bf(a.x);
        p.y = ((unsigned int)f2bf(b.y) << 16) | (unsigned int)f2bf(a.y);
        p.z = ((unsigned int)f2bf(b.z) << 16) | (unsigned int)f2bf(a.z);
        p.w = ((unsigned int)f2bf(b.w) << 16) | (unsigned int)f2bf(a.w);
        ((uint4*)rowp)[idx] = p;
    }
    __syncthreads();
    int f0 = half << 13;                       // 0 or 8192
#pragma unroll 4
    for (int it = 0; it < 8; ++it) {
        int f = f0 + threadIdx.x + it * 1024;
        const uint4* sp = (const uint4*)(packed + ((size_t)f << 4));
        float a0 = 0.f, a1 = 0.f;
#pragma unroll
        for (int q = 0; q < 4; ++q) {
            uint4 w = sp[q];
#define CONN(ww) { unsigned int p_ = rowp[(ww) & 0xffffu];                  \
                   float v_ = __uint_as_float((ww) & 0xffff0000u);          \
                   a0 += __uint_as_float(p_ << 16) * v_;                    \
                   a1 += __uint_as_float(p_ & 0xffff0000u) * v_; }
            CONN(w.x) CONN(w.y) CONN(w.z) CONN(w.w)
#undef CONN
        }
        out[(size_t)bs0 * F_ + f] = a0;
        out[(size_t)(bs0 + 1) * F_ + f] = a1;
    }
}

extern "C" void kernel_launch(void* const* d_in, const int* in_sizes, int n_in,
                              void* d_out, int out_size, void* d_ws, size_t ws_size,
                              hipStream_t stream) {
    const float* up   = (const float*)d_in[0];  // up_facts   [B,S,F]
    const float* enc  = (const float*)d_in[1];  // down_encoder [F,D]
    const float* dec  = (const float*)d_in[2];  // up_decoder [D,F]
    // d_in[3] = i_indices, unused: i[m] = m >> 4 by construction
    const int*   jidx = (const int*)d_in[4];    // j_indices  [M]
    float*       out  = (float*)d_out;

    size_t dec8_bytes  = (size_t)F_ * D_;                 // 12.6 MB (int8)
    size_t scale_bytes = (size_t)F_ * 16 * sizeof(float); // 1 MB
    unsigned char* dec8   = (unsigned char*)d_ws;
    float*         scales = (float*)((char*)d_ws + dec8_bytes);
    unsigned int*  packed = (unsigned int*)((char*)d_ws + dec8_bytes + scale_bytes);

    k_transpose_i8<<<dim3(F_ / 64, D_ / 64), 256, 0, stream>>>(dec, dec8, scales);
    k_values<<<F_ / 2, 256, 0, stream>>>(enc, dec8, scales, jidx, packed);
    k_out<<<BS_, 1024, 0, stream>>>(up, packed, out);
}